// Round 12
// baseline (39.476 us; speedup 1.0000x reference)
//
#include <hip/hip_runtime.h>

#define N 384
#define DXD 128
#define DZD 32
#define BSPLIT 6
#define BCH (N / BSPLIT)           // 64 b-values per chunk
#define NORM (2.0f / 1443840.0f)   // 2 / (n*K*(2n-3K-1)), n=384, K=5
#define CX 24.0f                   // exponent centers (cancel in sigma ratio)
#define CZ 12.0f

// ---------------------------------------------------------------------------
// Kernel A: LDS-tiled transpose, coalesced both sides; zeroes out[0].
__global__ void __launch_bounds__(256) transpose_xz(const float* __restrict__ X,
                                                    const float* __restrict__ Z,
                                                    float* __restrict__ XT,
                                                    float* __restrict__ ZT,
                                                    float* __restrict__ out) {
    __shared__ float tile[64][129];
    const int b = blockIdx.x;
    const int t = threadIdx.x;
    if (b == 0 && t == 0) out[0] = 0.f;

    if (b < 6) {
        const int R = b * 64;
        #pragma unroll
        for (int r0 = 0; r0 < 64; r0 += 8) {
            const int r = r0 + (t >> 5);
            const int c = (t & 31) * 4;
            float4 v = *reinterpret_cast<const float4*>(X + (size_t)(R + r) * DXD + c);
            tile[r][c] = v.x; tile[r][c + 1] = v.y; tile[r][c + 2] = v.z; tile[r][c + 3] = v.w;
        }
        __syncthreads();
        const int l = t & 63, w = t >> 6;
        #pragma unroll
        for (int k0 = 0; k0 < DXD; k0 += 4)
            XT[(size_t)(k0 + w) * N + R + l] = tile[l][k0 + w];
    } else {
        const int R = (b - 6) * 64;
        #pragma unroll
        for (int r0 = 0; r0 < 64; r0 += 32) {
            const int r = r0 + (t >> 3);
            const int c = (t & 7) * 4;
            float4 v = *reinterpret_cast<const float4*>(Z + (size_t)(R + r) * DZD + c);
            tile[r][c] = v.x; tile[r][c + 1] = v.y; tile[r][c + 2] = v.z; tile[r][c + 3] = v.w;
        }
        __syncthreads();
        const int l = t & 63, w = t >> 6;
        #pragma unroll
        for (int k0 = 0; k0 < DZD; k0 += 4)
            ZT[(size_t)(k0 + w) * N + R + l] = tile[l][k0 + w];
    }
}

// ---------------------------------------------------------------------------
// Kernel B: EX[i][a] = exp(2*dX(i,a) - CX), EZ likewise with CZ.
// XT/ZT reads coalesced (lane->a); X_i/Z_i wave-uniform (scalar path).
__global__ void __launch_bounds__(192) exp_rows(const float* __restrict__ X,
                                                const float* __restrict__ Z,
                                                const float* __restrict__ XT,
                                                const float* __restrict__ ZT,
                                                float* __restrict__ EX,
                                                float* __restrict__ EZ) {
    const int i = blockIdx.x >> 1;
    const int a = (blockIdx.x & 1) * 192 + threadIdx.x;

    const float* __restrict__ Xi = X + (size_t)i * DXD;
    float sq = 0.f;
    #pragma unroll 16
    for (int k = 0; k < DXD; ++k) {
        float v = XT[(size_t)k * N + a] - Xi[k];
        sq += v * v;
    }
    float dx = (sq > 1e-12f) ? sqrtf(sq) : 0.f;
    EX[(size_t)i * N + a] = __expf(2.f * dx - CX);

    const float* __restrict__ Zi = Z + (size_t)i * DZD;
    float sqz = 0.f;
    #pragma unroll 16
    for (int k = 0; k < DZD; ++k) {
        float v = ZT[(size_t)k * N + a] - Zi[k];
        sqz += v * v;
    }
    float dz = (sqz > 1e-12f) ? sqrtf(sqz) : 0.f;
    EZ[(size_t)i * N + a] = __expf(2.f * dz - CZ);
}

// ---------------------------------------------------------------------------
// Kernel C: partial sigmoid sums. Block (c,i): b-chunk c (64 b's), all 384 a
// (2 per thread). No LDS -> 10 blocks/CU co-resident, ~27 waves/CU.
// sigma((d_b-d_a)/tau) = e_b / (e_b + e_a); e_b reads uniform (L1 broadcast).
__global__ void __launch_bounds__(192) loss_part(const float* __restrict__ EX,
                                                 const float* __restrict__ EZ,
                                                 float* __restrict__ sxp,
                                                 float* __restrict__ szp) {
    const int c = blockIdx.x;          // 0..BSPLIT-1
    const int i = blockIdx.y;
    const int t = threadIdx.x;

    const float* __restrict__ exrow = EX + (size_t)i * N;
    const float* __restrict__ ezrow = EZ + (size_t)i * N;
    const float exa0 = exrow[t], exa1 = exrow[t + 192];   // coalesced
    const float eza0 = ezrow[t], eza1 = ezrow[t + 192];

    const float4* __restrict__ ex4 = reinterpret_cast<const float4*>(exrow + c * BCH);
    const float4* __restrict__ ez4 = reinterpret_cast<const float4*>(ezrow + c * BCH);
    float sx0 = 0.f, sx1 = 0.f, sz0 = 0.f, sz1 = 0.f;
    #pragma unroll 4
    for (int b = 0; b < BCH / 4; ++b) {   // 16 iters x 16 sigmoids
        float4 e = ex4[b];                 // uniform -> single-line broadcast
        float4 f = ez4[b];
        sx0 += e.x * __builtin_amdgcn_rcpf(e.x + exa0);
        sx1 += e.x * __builtin_amdgcn_rcpf(e.x + exa1);
        sz0 += f.x * __builtin_amdgcn_rcpf(f.x + eza0);
        sz1 += f.x * __builtin_amdgcn_rcpf(f.x + eza1);
        sx0 += e.y * __builtin_amdgcn_rcpf(e.y + exa0);
        sx1 += e.y * __builtin_amdgcn_rcpf(e.y + exa1);
        sz0 += f.y * __builtin_amdgcn_rcpf(f.y + eza0);
        sz1 += f.y * __builtin_amdgcn_rcpf(f.y + eza1);
        sx0 += e.z * __builtin_amdgcn_rcpf(e.z + exa0);
        sx1 += e.z * __builtin_amdgcn_rcpf(e.z + exa1);
        sz0 += f.z * __builtin_amdgcn_rcpf(f.z + eza0);
        sz1 += f.z * __builtin_amdgcn_rcpf(f.z + eza1);
        sx0 += e.w * __builtin_amdgcn_rcpf(e.w + exa0);
        sx1 += e.w * __builtin_amdgcn_rcpf(e.w + exa1);
        sz0 += f.w * __builtin_amdgcn_rcpf(f.w + eza0);
        sz1 += f.w * __builtin_amdgcn_rcpf(f.w + eza1);
    }

    const size_t base = ((size_t)c * N + i) * N;
    sxp[base + t] = sx0;  sxp[base + t + 192] = sx1;   // coalesced
    szp[base + t] = sz0;  szp[base + t + 192] = sz1;
}

// ---------------------------------------------------------------------------
// Kernel D: combine partials, apply nonlinearity, reduce, atomic add.
__global__ void __launch_bounds__(N) combine(const float* __restrict__ sxp,
                                             const float* __restrict__ szp,
                                             float* __restrict__ out) {
    __shared__ float red[N / 64];
    const int i = blockIdx.x;
    const int t = threadIdx.x;     // a = t

    float sx = 0.f, sz = 0.f;
    #pragma unroll
    for (int c = 0; c < BSPLIT; ++c) {
        sx += sxp[((size_t)c * N + i) * N + t];
        sz += szp[((size_t)c * N + i) * N + t];
    }
    // intrusion = relu(1+sx-K); W = clamp((K+1-(1+sz))/K, 0, 1)
    float intr = fmaxf(sx - 4.f, 0.f);
    float W = fminf(fmaxf((5.f - sz) * 0.2f, 0.f), 1.f);
    float contrib = intr * (1.f - W);

    #pragma unroll
    for (int off = 32; off > 0; off >>= 1)
        contrib += __shfl_down(contrib, off, 64);
    const int lane = t & 63, w = t >> 6;
    if (lane == 0) red[w] = contrib;
    __syncthreads();
    if (t == 0) {
        float s = 0.f;
        #pragma unroll
        for (int w2 = 0; w2 < N / 64; ++w2) s += red[w2];
        atomicAdd(out, s * NORM);
    }
}

extern "C" void kernel_launch(void* const* d_in, const int* in_sizes, int n_in,
                              void* d_out, int out_size, void* d_ws, size_t ws_size,
                              hipStream_t stream) {
    const float* X = (const float*)d_in[0];   // (384, 128) f32
    const float* Z = (const float*)d_in[1];   // (384, 32)  f32
    float* out = (float*)d_out;

    float* XT = (float*)d_ws;                       // 128*384
    float* ZT = XT + (size_t)DXD * N;               // 32*384
    float* EX = ZT + (size_t)DZD * N;               // 384*384
    float* EZ = EX + (size_t)N * N;                 // 384*384
    float* sxp = EZ + (size_t)N * N;                // 6*384*384
    float* szp = sxp + (size_t)BSPLIT * N * N;      // 6*384*384

    transpose_xz<<<12, 256, 0, stream>>>(X, Z, XT, ZT, out);
    exp_rows<<<2 * N, 192, 0, stream>>>(X, Z, XT, ZT, EX, EZ);
    loss_part<<<dim3(BSPLIT, N), 192, 0, stream>>>(EX, EZ, sxp, szp);
    combine<<<N, N, 0, stream>>>(sxp, szp, out);
}

// Round 13
// 34.485 us; speedup vs baseline: 1.1447x; 1.1447x over previous
//
#include <hip/hip_runtime.h>

#define N 384
#define DXD 128
#define DZD 32
#define NPAIR (N / 2)              // 192 b-pairs
#define NORM (2.0f / 1443840.0f)   // 2 / (n*K*(2n-3K-1)), n=384, K=5
#define CX 24.0f                   // exponent centers (cancel in sigma ratio)
#define CZ 12.0f

// ---------------------------------------------------------------------------
// Kernel A: LDS-tiled transpose, coalesced both sides; zeroes out[0].
__global__ void __launch_bounds__(256) transpose_xz(const float* __restrict__ X,
                                                    const float* __restrict__ Z,
                                                    float* __restrict__ XT,
                                                    float* __restrict__ ZT,
                                                    float* __restrict__ out) {
    __shared__ float tile[64][129];
    const int b = blockIdx.x;
    const int t = threadIdx.x;
    if (b == 0 && t == 0) out[0] = 0.f;

    if (b < 6) {
        const int R = b * 64;
        #pragma unroll
        for (int r0 = 0; r0 < 64; r0 += 8) {
            const int r = r0 + (t >> 5);
            const int c = (t & 31) * 4;
            float4 v = *reinterpret_cast<const float4*>(X + (size_t)(R + r) * DXD + c);
            tile[r][c] = v.x; tile[r][c + 1] = v.y; tile[r][c + 2] = v.z; tile[r][c + 3] = v.w;
        }
        __syncthreads();
        const int l = t & 63, w = t >> 6;
        #pragma unroll
        for (int k0 = 0; k0 < DXD; k0 += 4)
            XT[(size_t)(k0 + w) * N + R + l] = tile[l][k0 + w];
    } else {
        const int R = (b - 6) * 64;
        #pragma unroll
        for (int r0 = 0; r0 < 64; r0 += 32) {
            const int r = r0 + (t >> 3);
            const int c = (t & 7) * 4;
            float4 v = *reinterpret_cast<const float4*>(Z + (size_t)(R + r) * DZD + c);
            tile[r][c] = v.x; tile[r][c + 1] = v.y; tile[r][c + 2] = v.z; tile[r][c + 3] = v.w;
        }
        __syncthreads();
        const int l = t & 63, w = t >> 6;
        #pragma unroll
        for (int k0 = 0; k0 < DZD; k0 += 4)
            ZT[(size_t)(k0 + w) * N + R + l] = tile[l][k0 + w];
    }
}

// ---------------------------------------------------------------------------
// Kernel B: fused per-row loss with PAIRED sigmoids.
// sigma_p + sigma_q = (2P + ea*S) / (P + ea*S + ea^2), P=e_p*e_q, S=e_p+e_q.
// P,S tables computed once per row, shared by all 384 a's -> 1 rcp / 2 sigmoids.
__global__ void __launch_bounds__(192) fused_loss(const float* __restrict__ X,
                                                  const float* __restrict__ Z,
                                                  const float* __restrict__ XT,
                                                  const float* __restrict__ ZT,
                                                  float* __restrict__ out) {
    __shared__ float ex[N]      __attribute__((aligned(16)));
    __shared__ float ez[N]      __attribute__((aligned(16)));
    __shared__ float pxs[NPAIR] __attribute__((aligned(16)));
    __shared__ float sxs[NPAIR] __attribute__((aligned(16)));
    __shared__ float pzs[NPAIR] __attribute__((aligned(16)));
    __shared__ float szs[NPAIR] __attribute__((aligned(16)));
    __shared__ float red[3];
    const int i = blockIdx.x >> 1;
    const int half = blockIdx.x & 1;
    const int t = threadIdx.x;

    const float* __restrict__ Xi = X + (size_t)i * DXD;   // uniform -> scalar path
    const float* __restrict__ Zi = Z + (size_t)i * DZD;

    // phase 1: e-tables (each thread fills entries t and t+192)
    #pragma unroll
    for (int rep = 0; rep < 2; ++rep) {
        const int a = rep * 192 + t;
        float sq = 0.f;
        #pragma unroll 16
        for (int k = 0; k < DXD; ++k) {
            float v = XT[(size_t)k * N + a] - Xi[k];      // coalesced across lanes
            sq += v * v;
        }
        float dx = (sq > 1e-12f) ? sqrtf(sq) : 0.f;
        ex[a] = __expf(2.f * dx - CX);

        float sqz = 0.f;
        #pragma unroll 16
        for (int k = 0; k < DZD; ++k) {
            float v = ZT[(size_t)k * N + a] - Zi[k];
            sqz += v * v;
        }
        float dz = (sqz > 1e-12f) ? sqrtf(sqz) : 0.f;
        ez[a] = __expf(2.f * dz - CZ);
    }
    __syncthreads();

    // phase 1.5: pair tables (thread t builds pair t for X and Z)
    {
        float e0 = ex[2 * t], e1 = ex[2 * t + 1];
        pxs[t] = e0 * e1;  sxs[t] = e0 + e1;
        float f0 = ez[2 * t], f1 = ez[2 * t + 1];
        pzs[t] = f0 * f1;  szs[t] = f0 + f1;
    }
    __syncthreads();

    // phase 2: paired b-loop; this thread's a = half*192 + t
    const int a = half * 192 + t;
    const float ea = ex[a], ea2 = ea * ea;
    const float fa = ez[a], fa2 = fa * fa;
    const float4* __restrict__ px4 = reinterpret_cast<const float4*>(pxs);
    const float4* __restrict__ sx4 = reinterpret_cast<const float4*>(sxs);
    const float4* __restrict__ pz4 = reinterpret_cast<const float4*>(pzs);
    const float4* __restrict__ sz4 = reinterpret_cast<const float4*>(szs);
    float ax0 = 0.f, ax1 = 0.f, ax2 = 0.f, ax3 = 0.f;
    float az0 = 0.f, az1 = 0.f, az2 = 0.f, az3 = 0.f;
    #pragma unroll 4
    for (int p = 0; p < NPAIR / 4; ++p) {   // 48 iters x 4 pairs x 2 matrices
        float4 P = px4[p];                   // uniform -> LDS broadcast
        float4 S = sx4[p];
        float4 Q = pz4[p];
        float4 T = sz4[p];
        float t0, t1, t2, t3;
        t0 = fmaf(ea, S.x, P.x); ax0 += (t0 + P.x) * __builtin_amdgcn_rcpf(t0 + ea2);
        t1 = fmaf(ea, S.y, P.y); ax1 += (t1 + P.y) * __builtin_amdgcn_rcpf(t1 + ea2);
        t2 = fmaf(ea, S.z, P.z); ax2 += (t2 + P.z) * __builtin_amdgcn_rcpf(t2 + ea2);
        t3 = fmaf(ea, S.w, P.w); ax3 += (t3 + P.w) * __builtin_amdgcn_rcpf(t3 + ea2);
        t0 = fmaf(fa, T.x, Q.x); az0 += (t0 + Q.x) * __builtin_amdgcn_rcpf(t0 + fa2);
        t1 = fmaf(fa, T.y, Q.y); az1 += (t1 + Q.y) * __builtin_amdgcn_rcpf(t1 + fa2);
        t2 = fmaf(fa, T.z, Q.z); az2 += (t2 + Q.z) * __builtin_amdgcn_rcpf(t2 + fa2);
        t3 = fmaf(fa, T.w, Q.w); az3 += (t3 + Q.w) * __builtin_amdgcn_rcpf(t3 + fa2);
    }
    float sx = (ax0 + ax1) + (ax2 + ax3);    // = sum_b sigmoid_X
    float sz = (az0 + az1) + (az2 + az3);    // = sum_b sigmoid_Z

    // intrusion = relu(1+sx-K); W = clamp((K+1-(1+sz))/K, 0, 1)
    float intr = fmaxf(sx - 4.f, 0.f);
    float W = fminf(fmaxf((5.f - sz) * 0.2f, 0.f), 1.f);
    float contrib = intr * (1.f - W);

    #pragma unroll
    for (int off = 32; off > 0; off >>= 1)
        contrib += __shfl_down(contrib, off, 64);
    const int lane = t & 63, w = t >> 6;
    if (lane == 0) red[w] = contrib;
    __syncthreads();
    if (t == 0) atomicAdd(out, (red[0] + red[1] + red[2]) * NORM);
}

extern "C" void kernel_launch(void* const* d_in, const int* in_sizes, int n_in,
                              void* d_out, int out_size, void* d_ws, size_t ws_size,
                              hipStream_t stream) {
    const float* X = (const float*)d_in[0];   // (384, 128) f32
    const float* Z = (const float*)d_in[1];   // (384, 32)  f32
    float* out = (float*)d_out;

    float* XT = (float*)d_ws;                  // 128*384
    float* ZT = XT + (size_t)DXD * N;          // 32*384

    transpose_xz<<<12, 256, 0, stream>>>(X, Z, XT, ZT, out);
    fused_loss<<<2 * N, 192, 0, stream>>>(X, Z, XT, ZT, out);
}